// Round 3
// baseline (530.929 us; speedup 1.0000x reference)
//
#include <hip/hip_runtime.h>
#include <hip/hip_bf16.h>
#include <stdint.h>

#define B_  2
#define S_  2048
#define H_  1024
#define NH_ 16
#define DH_ 64

typedef __attribute__((ext_vector_type(8))) short   s16x8;
typedef __attribute__((ext_vector_type(8))) __bf16  bf16x8;
typedef __attribute__((ext_vector_type(4))) float   f32x4;

__device__ __forceinline__ unsigned short f2bf(float f) {
  return __builtin_bit_cast(unsigned short, __float2bfloat16(f));
}

__device__ __forceinline__ void gll16(const void* g, void* l) {
  __builtin_amdgcn_global_load_lds(
      (__attribute__((address_space(1))) void*)(g),
      (__attribute__((address_space(3))) void*)(l), 16, 0, 0);
}

__device__ __forceinline__ f32x4 mfma_bf16(s16x8 a, s16x8 b, f32x4 c) {
  return __builtin_amdgcn_mfma_f32_16x16x32_bf16(
      __builtin_bit_cast(bf16x8, a), __builtin_bit_cast(bf16x8, b), c, 0, 0, 0);
}

// ---------------------------------------------------------------- convert
__global__ __launch_bounds__(256) void cvt_kernel(const float* __restrict__ src,
                                                  unsigned short* __restrict__ dst,
                                                  int n4, float scale) {
  int i = blockIdx.x * blockDim.x + threadIdx.x;
  int stride = gridDim.x * blockDim.x;
  for (; i < n4; i += stride) {
    float4 f = reinterpret_cast<const float4*>(src)[i];
    ushort4 o;
    o.x = f2bf(f.x * scale); o.y = f2bf(f.y * scale);
    o.z = f2bf(f.z * scale); o.w = f2bf(f.w * scale);
    reinterpret_cast<ushort4*>(dst)[i] = o;
  }
}

// ---------------------------------------------------------------- QKV GEMM
// C[m][n] = sum_k hs[m][k] * W[n][k] + bias[n]   (bt-GEMM, both row-major)
// z=0 -> Q (pre-scaled by 1/8 via Wq,bq) [B,NH,S,DH]; z=1 -> K same layout;
// z=2 -> V stored transposed [B,NH,DH,S]
__global__ __launch_bounds__(256) void qkv_gemm(
    const unsigned short* __restrict__ hsb,   // [4096][1024] bf16
    const unsigned short* __restrict__ Wb,    // [3][1024][1024] bf16
    const float* __restrict__ bq, const float* __restrict__ bk,
    const float* __restrict__ bv,
    unsigned short* __restrict__ Qb, unsigned short* __restrict__ Kb,
    unsigned short* __restrict__ Vtb)
{
  __shared__ alignas(16) unsigned short lA[128 * 64];
  __shared__ alignas(16) unsigned short lB[128 * 64];

  const int tid  = threadIdx.x;
  const int lane = tid & 63;
  const int wid  = tid >> 6;
  const int wrow = wid >> 1, wcol = wid & 1;
  // bijective XCD swizzle: 768 = 8 * 96; chunk of 96 = 3 (n,z) panels per XCD
  const int flat = blockIdx.x;
  const int swz  = (flat & 7) * 96 + (flat >> 3);
  const int m0 = (swz & 31) * 128;
  const int n0 = ((swz >> 5) & 7) * 128;
  const int z  = swz >> 8;
  const int lr = lane & 15;
  const int lq = lane >> 4;

  const unsigned short* Wz = Wb + (size_t)z * (H_ * H_);

  f32x4 acc[4][4];
  #pragma unroll
  for (int i = 0; i < 4; ++i)
    #pragma unroll
    for (int j = 0; j < 4; ++j) acc[i][j] = {0.f, 0.f, 0.f, 0.f};

  for (int kt = 0; kt < H_ / 64; ++kt) {
    const int k0 = kt * 64;
    __syncthreads();
    // stage 128x64 bf16 tiles, linear LDS dest, inverse-swizzled global src
    #pragma unroll
    for (int i = 0; i < 4; ++i) {
      int idx = i * 256 + tid;
      int row = idx >> 3, cs = idx & 7, c = cs ^ (row & 7);
      gll16(hsb + (size_t)(m0 + row) * H_ + k0 + c * 8, (char*)lA + idx * 16);
    }
    #pragma unroll
    for (int i = 0; i < 4; ++i) {
      int idx = i * 256 + tid;
      int row = idx >> 3, cs = idx & 7, c = cs ^ (row & 7);
      gll16(Wz + (size_t)(n0 + row) * H_ + k0 + c * 8, (char*)lB + idx * 16);
    }
    __syncthreads();

    #pragma unroll
    for (int kk = 0; kk < 2; ++kk) {
      s16x8 af[4], bfr[4];
      #pragma unroll
      for (int mi = 0; mi < 4; ++mi) {
        int row = wrow * 64 + mi * 16 + lr;
        int ch  = (kk * 4 + lq) ^ (row & 7);
        af[mi] = *reinterpret_cast<const s16x8*>((const char*)lA + row * 128 + ch * 16);
      }
      #pragma unroll
      for (int ni = 0; ni < 4; ++ni) {
        int row = wcol * 64 + ni * 16 + lr;
        int ch  = (kk * 4 + lq) ^ (row & 7);
        bfr[ni] = *reinterpret_cast<const s16x8*>((const char*)lB + row * 128 + ch * 16);
      }
      #pragma unroll
      for (int mi = 0; mi < 4; ++mi)
        #pragma unroll
        for (int ni = 0; ni < 4; ++ni)
          acc[mi][ni] = mfma_bf16(af[mi], bfr[ni], acc[mi][ni]);
    }
  }

  const float* bvec = (z == 0) ? bq : (z == 1) ? bk : bv;
  const float bscale = (z == 0) ? 0.125f : 1.0f;

  // C/D layout: col n = lane&15, row m = (lane>>4)*4 + j
  #pragma unroll
  for (int ni = 0; ni < 4; ++ni) {
    int n = n0 + wcol * 64 + ni * 16 + lr;
    float bn = bvec[n] * bscale;
    int h = n >> 6, d = n & 63;
    #pragma unroll
    for (int mi = 0; mi < 4; ++mi) {
      int mbase = m0 + wrow * 64 + mi * 16 + lq * 4;
      int b = mbase >> 11, s = mbase & 2047;
      if (z == 2) {
        ushort4 o;
        o.x = f2bf(acc[mi][ni][0] + bn);
        o.y = f2bf(acc[mi][ni][1] + bn);
        o.z = f2bf(acc[mi][ni][2] + bn);
        o.w = f2bf(acc[mi][ni][3] + bn);
        *reinterpret_cast<ushort4*>(Vtb + ((size_t)(b * NH_ + h) * DH_ + d) * S_ + s) = o;
      } else {
        unsigned short* dst = (z == 0) ? Qb : Kb;
        #pragma unroll
        for (int j = 0; j < 4; ++j)
          dst[((size_t)(b * NH_ + h) * S_ + (s + j)) * DH_ + d] =
              f2bf(acc[mi][ni][j] + bn);
      }
    }
  }
}

// ---------------------------------------------------------------- attention
// per block: 64 q-rows (4 waves x 16), KBLK=64 flash loop, double-buffered K/V.
// swapped QK^T: D[kk][q] = mfma(K_frag, Q_frag)  -> softmax state per q=lane&15
// PV: D[d][q]  = mfma(Vt_frag, P_frag)           -> same column mapping
__global__ __launch_bounds__(256) void attn_kernel(
    const unsigned short* __restrict__ Qb,
    const unsigned short* __restrict__ Kb,
    const unsigned short* __restrict__ Vtb,
    const float* __restrict__ bias,
    float* __restrict__ out)
{
  __shared__ alignas(16) unsigned short lK[2][64 * 64];
  __shared__ alignas(16) unsigned short lV[2][64 * 64];
  __shared__ alignas(16) unsigned short lP[4][16 * 72];   // padded stride 72

  const int tid  = threadIdx.x;
  const int lane = tid & 63;
  const int wid  = tid >> 6;
  const int lr = lane & 15, lq = lane >> 4;

  // bijective XCD swizzle: 1024 = 8 * 128; each XCD gets 4 full (b,h) groups
  const int flat = blockIdx.x;
  const int swz  = (flat & 7) * 128 + (flat >> 3);
  const int q0 = (swz & 31) * 64;
  const int h  = (swz >> 5) & 15;
  const int b  = swz >> 9;
  const int bh = b * NH_ + h;
  const int qrow = q0 + wid * 16 + lr;

  // Q fragments (B operand): Q[qrow][kt*32 + lq*8 + j]  (pre-scaled by 1/8)
  s16x8 qf[2];
  #pragma unroll
  for (int kt = 0; kt < 2; ++kt)
    qf[kt] = *reinterpret_cast<const s16x8*>(
        Qb + ((size_t)bh * S_ + qrow) * DH_ + kt * 32 + lq * 8);

  float m_run = -INFINITY, l_run = 0.0f;
  f32x4 acc_o[4];
  #pragma unroll
  for (int i = 0; i < 4; ++i) acc_o[i] = {0.f, 0.f, 0.f, 0.f};

  const float* brow = bias + ((size_t)h * S_ + qrow) * S_;
  unsigned short* Pw = &lP[wid][0];

  auto stage = [&](int buf, int kb) {
    #pragma unroll
    for (int i = 0; i < 2; ++i) {
      int idx = i * 256 + tid;
      int row = idx >> 3, cs = idx & 7, c = cs ^ (row & 7);
      gll16(Kb + ((size_t)bh * S_ + kb * 64 + row) * DH_ + c * 8,
            (char*)lK[buf] + idx * 16);
      gll16(Vtb + ((size_t)bh * DH_ + row) * S_ + kb * 64 + c * 8,
            (char*)lV[buf] + idx * 16);
    }
  };

  // prologue: stage tile 0, prefetch bias tile 0
  stage(0, 0);
  float4 b4c[4];
  #pragma unroll
  for (int ct = 0; ct < 4; ++ct)
    b4c[ct] = *reinterpret_cast<const float4*>(brow + ct * 16 + lq * 4);
  __syncthreads();

  for (int kb = 0; kb < S_ / 64; ++kb) {
    const int cur = kb & 1;

    // issue next-tile staging + bias prefetch before compute (2-phase pipeline)
    if (kb + 1 < S_ / 64) stage(cur ^ 1, kb + 1);
    float4 b4n[4];
    {
      int kbn = (kb + 1 < S_ / 64) ? kb + 1 : kb;
      #pragma unroll
      for (int ct = 0; ct < 4; ++ct)
        b4n[ct] = *reinterpret_cast<const float4*>(brow + kbn * 64 + ct * 16 + lq * 4);
    }

    // QK^T from lK[cur]
    f32x4 accs[4];
    #pragma unroll
    for (int ct = 0; ct < 4; ++ct) accs[ct] = {0.f, 0.f, 0.f, 0.f};
    #pragma unroll
    for (int ct = 0; ct < 4; ++ct) {
      #pragma unroll
      for (int kt = 0; kt < 2; ++kt) {
        int row = ct * 16 + lr;
        int ch  = (kt * 4 + lq) ^ (row & 7);
        s16x8 kf = *reinterpret_cast<const s16x8*>((const char*)lK[cur] + row * 128 + ch * 16);
        accs[ct] = mfma_bf16(kf, qf[kt], accs[ct]);
      }
    }

    // scores + bias (Q pre-scaled, no per-element scale here)
    float p[16];
    #pragma unroll
    for (int ct = 0; ct < 4; ++ct) {
      p[ct * 4 + 0] = accs[ct][0] + b4c[ct].x;
      p[ct * 4 + 1] = accs[ct][1] + b4c[ct].y;
      p[ct * 4 + 2] = accs[ct][2] + b4c[ct].z;
      p[ct * 4 + 3] = accs[ct][3] + b4c[ct].w;
    }
    float tmax = -INFINITY;
    #pragma unroll
    for (int i = 0; i < 16; ++i) tmax = fmaxf(tmax, p[i]);
    tmax = fmaxf(tmax, __shfl_xor(tmax, 16));
    tmax = fmaxf(tmax, __shfl_xor(tmax, 32));

    // defer-max (T13): rescale only when the running max grows by > 8
    if (!__all(tmax - m_run <= 8.0f)) {
      float m_new = fmaxf(m_run, tmax);
      float alpha = __expf(m_run - m_new);   // first iter: exp(-inf)=0
      l_run *= alpha;
      #pragma unroll
      for (int i = 0; i < 4; ++i) {
        acc_o[i][0] *= alpha; acc_o[i][1] *= alpha;
        acc_o[i][2] *= alpha; acc_o[i][3] *= alpha;
      }
      m_run = m_new;
    }

    float lsum = 0.0f;
    #pragma unroll
    for (int i = 0; i < 16; ++i) { p[i] = __expf(p[i] - m_run); lsum += p[i]; }
    lsum += __shfl_xor(lsum, 16);
    lsum += __shfl_xor(lsum, 32);
    l_run += lsum;

    // P -> LDS (row q=lr, cols ct*16 + lq*4 + r), per-wave buffer
    #pragma unroll
    for (int ct = 0; ct < 4; ++ct) {
      ushort4 o;
      o.x = f2bf(p[ct * 4 + 0]); o.y = f2bf(p[ct * 4 + 1]);
      o.z = f2bf(p[ct * 4 + 2]); o.w = f2bf(p[ct * 4 + 3]);
      *reinterpret_cast<ushort4*>(Pw + lr * 72 + ct * 16 + lq * 4) = o;
    }

    // PV from lV[cur]
    #pragma unroll
    for (int kt = 0; kt < 2; ++kt) {
      s16x8 pf = *reinterpret_cast<const s16x8*>(Pw + lr * 72 + kt * 32 + lq * 8);
      #pragma unroll
      for (int df = 0; df < 4; ++df) {
        int row = df * 16 + lr;
        int ch  = (kt * 4 + lq) ^ (row & 7);
        s16x8 vf = *reinterpret_cast<const s16x8*>((const char*)lV[cur] + row * 128 + ch * 16);
        acc_o[df] = mfma_bf16(vf, pf, acc_o[df]);
      }
    }

    #pragma unroll
    for (int ct = 0; ct < 4; ++ct) b4c[ct] = b4n[ct];

    __syncthreads();   // drains next-tile staging; frees lK/lV[cur] for overwrite
  }

  // epilogue: acc_o[df][j] = ctx^T[d = df*16+lq*4+j][q = lr]
  float rl = 1.0f / l_run;
  float* orow = out + ((size_t)b * S_ + qrow) * H_ + h * DH_;
  #pragma unroll
  for (int df = 0; df < 4; ++df) {
    float4 o;
    o.x = acc_o[df][0] * rl; o.y = acc_o[df][1] * rl;
    o.z = acc_o[df][2] * rl; o.w = acc_o[df][3] * rl;
    *reinterpret_cast<float4*>(orow + df * 16 + lq * 4) = o;
  }
}

// ---------------------------------------------------------------- launch
extern "C" void kernel_launch(void* const* d_in, const int* in_sizes, int n_in,
                              void* d_out, int out_size, void* d_ws, size_t ws_size,
                              hipStream_t stream) {
  const float* hs   = (const float*)d_in[0];
  const float* bias = (const float*)d_in[1];
  const float* Wq   = (const float*)d_in[2];
  const float* bq   = (const float*)d_in[3];
  const float* Wk   = (const float*)d_in[4];
  const float* bk   = (const float*)d_in[5];
  const float* Wv   = (const float*)d_in[6];
  const float* bv   = (const float*)d_in[7];
  float* out = (float*)d_out;

  unsigned short* ws  = (unsigned short*)d_ws;
  unsigned short* hsb = ws;                                    // 8,388,608 elems
  unsigned short* Wb  = hsb + (size_t)B_ * S_ * H_;            // 3,145,728
  unsigned short* Qb  = Wb + (size_t)3 * H_ * H_;              // 8,388,608
  unsigned short* Kb  = Qb + (size_t)B_ * S_ * H_;             // 8,388,608
  unsigned short* Vtb = Kb + (size_t)B_ * S_ * H_;             // 8,388,608
  (void)in_sizes; (void)n_in; (void)out_size; (void)ws_size;

  cvt_kernel<<<2048, 256, 0, stream>>>(hs, hsb, (B_ * S_ * H_) / 4, 1.0f);
  cvt_kernel<<<1024, 256, 0, stream>>>(Wq, Wb, (H_ * H_) / 4, 0.125f);  // fold 1/sqrt(DH)
  cvt_kernel<<<1024, 256, 0, stream>>>(Wk, Wb + H_ * H_, (H_ * H_) / 4, 1.0f);
  cvt_kernel<<<1024, 256, 0, stream>>>(Wv, Wb + 2 * H_ * H_, (H_ * H_) / 4, 1.0f);

  qkv_gemm<<<768, 256, 0, stream>>>(hsb, Wb, bq, bk, bv, Qb, Kb, Vtb);

  attn_kernel<<<1024, 256, 0, stream>>>(Qb, Kb, Vtb, bias, out);
}